// Round 13
// baseline (236.733 us; speedup 1.0000x reference)
//
#include <hip/hip_runtime.h>

namespace {

constexpr float kScale = 0.17677669529663687f;  // 32^-0.5

typedef __attribute__((ext_vector_type(8))) short bf16x8;
typedef __attribute__((ext_vector_type(4))) short bf16x4;
typedef __attribute__((ext_vector_type(4))) float f32x4;

// RNE fp32 -> bf16 (bit pattern in short)
__device__ __forceinline__ short bf_hi(float x) {
  unsigned u = __float_as_uint(x);
  return (short)((u + 0x7FFFu + ((u >> 16) & 1u)) >> 16);
}
// residual term: bf16(x - float(bf16(x)))
__device__ __forceinline__ short bf_lo(float x) {
  unsigned u = __float_as_uint(x);
  unsigned hi = (u + 0x7FFFu + ((u >> 16) & 1u)) & 0xFFFF0000u;
  float r = x - __uint_as_float(hi);
  unsigned u2 = __float_as_uint(r);
  return (short)((u2 + 0x7FFFu + ((u2 >> 16) & 1u)) >> 16);
}

__device__ __forceinline__ bf16x8 cvt8v(const float4 f0, const float4 f1,
                                        bool lo) {
  bf16x8 v;
  if (lo) {
    v[0] = bf_lo(f0.x); v[1] = bf_lo(f0.y); v[2] = bf_lo(f0.z);
    v[3] = bf_lo(f0.w); v[4] = bf_lo(f1.x); v[5] = bf_lo(f1.y);
    v[6] = bf_lo(f1.z); v[7] = bf_lo(f1.w);
  } else {
    v[0] = bf_hi(f0.x); v[1] = bf_hi(f0.y); v[2] = bf_hi(f0.z);
    v[3] = bf_hi(f0.w); v[4] = bf_hi(f1.x); v[5] = bf_hi(f1.y);
    v[6] = bf_hi(f1.z); v[7] = bf_hi(f1.w);
  }
  return v;
}

// ---- wsplit2: emit qkv B operand in per-chunk layout [72][256 col][32 k] --
__global__ __launch_bounds__(1024) void wsplit2_kernel(
    const float* __restrict__ w, short* __restrict__ wsplit2) {
  const int nc = blockIdx.x;  // 0..71
  const int ct = nc / 24, j = nc % 24;
  const int r = j >> 3, kc = j & 7;
  const bool lo = (r == 1);
  const int u = threadIdx.x;           // 0..1023
  const int col = u >> 2, kq = u & 3;  // 8 shorts per thread
  const float* src = &w[(size_t)(ct * 256 + col) * 256 + kc * 32 + kq * 8];
  const float4 f0 = *reinterpret_cast<const float4*>(src);
  const float4 f1 = *reinterpret_cast<const float4*>(src + 4);
  *reinterpret_cast<bf16x8*>(&wsplit2[(size_t)nc * 8192 + u * 8]) =
      cvt8v(f0, f1, lo);
}

// ---- pwsplit: same layout for proj_w: [24][256 col][32 k] -----------------
__global__ __launch_bounds__(1024) void pwsplit_kernel(
    const float* __restrict__ w, short* __restrict__ pw) {
  const int nc = blockIdx.x;  // 0..23
  const int r = nc >> 3, kc = nc & 7;
  const bool lo = (r == 1);
  const int u = threadIdx.x;
  const int col = u >> 2, kq = u & 3;
  const float* src = &w[(size_t)col * 256 + kc * 32 + kq * 8];
  const float4 f0 = *reinterpret_cast<const float4*>(src);
  const float4 f1 = *reinterpret_cast<const float4*>(src + 4);
  *reinterpret_cast<bf16x8*>(&pw[(size_t)nc * 8192 + u * 8]) =
      cvt8v(f0, f1, lo);
}

// ---------------- qkv GEMM via split-bf16 MFMA, 64-row panels --------------
// One block (512 thr = 8 waves) per 64-row panel; 66.6 KB LDS -> 2 blocks/CU
// = 4 waves/SIMD (2x R12's latency hiding). x panel read from HBM ONCE,
// split into [xh | xl] bf16 in LDS. Each wave owns 64 rows x 32 cols; B
// fragments load DIRECTLY from L2-resident wsplit2 (chunk layout == fragment
// layout, contiguous per-wave), 1-deep ping/pong, no barriers in K-loop.
__global__ __launch_bounds__(512, 4) void qkv_mfma_kernel(
    const float* __restrict__ x, const short* __restrict__ wsplit2,
    const float* __restrict__ bias, float* __restrict__ q,
    float* __restrict__ kk, float* __restrict__ v) {
  __shared__ short As[64][520];  // [row][xh(256) | xl(256)] -> 66.6 KB
  const int tid = threadIdx.x;
  const int row0 = blockIdx.x * 64;
  const int wave = tid >> 6, lane = tid & 63;
  const int wc = wave * 32;  // 8 waves x 32 cols = 256 cols per pass
  const int l15 = lane & 15, l4 = lane >> 4;

  // per-lane B fragment base: row (wc + f*16 + l15), k-slice l4*8
  const short* bbase = wsplit2 + (size_t)(wc + l15) * 32 + l4 * 8;
  bf16x8 bA[2], bB[2];
  auto bload = [&](int nc, bf16x8 (&b)[2]) {
#pragma unroll
    for (int f = 0; f < 2; ++f)
      b[f] = *reinterpret_cast<const bf16x8*>(bbase + (size_t)nc * 8192 +
                                              f * 512);
  };
  bload(0, bA);

  // stage A panel: 64 rows x 64 float4 = 4096 float4s, split to hi/lo
#pragma unroll 4
  for (int i = 0; i < 8; ++i) {
    const int f = tid + i * 512;             // float4 index
    const int r = f >> 6, c = (f & 63) * 4;  // row, col(0..252)
    const float4 a4 = *reinterpret_cast<const float4*>(
        &x[(size_t)(row0 + r) * 256 + c]);
    bf16x4 h, l;
    h[0] = bf_hi(a4.x); h[1] = bf_hi(a4.y); h[2] = bf_hi(a4.z);
    h[3] = bf_hi(a4.w);
    l[0] = bf_lo(a4.x); l[1] = bf_lo(a4.y); l[2] = bf_lo(a4.z);
    l[3] = bf_lo(a4.w);
    *reinterpret_cast<bf16x4*>(&As[r][c]) = h;
    *reinterpret_cast<bf16x4*>(&As[r][256 + c]) = l;
  }
  __syncthreads();  // the only barrier: As is read-only from here on

  f32x4 acc[4][2];
  // one chunk: prefetch nc+1 into pf, consume use
  auto step = [&](int nc, bf16x8 (&use)[2], bf16x8 (&pf)[2]) {
    if (nc + 1 < 72) bload(nc + 1, pf);
    const int j = nc % 24;
    const int r = j >> 3, kc = j & 7;
    const int aoff = (r == 2 ? 256 : 0) + kc * 32;
    bf16x8 af[4];
#pragma unroll
    for (int f = 0; f < 4; ++f)
      af[f] = *reinterpret_cast<const bf16x8*>(
          &As[f * 16 + l15][aoff + l4 * 8]);
#pragma unroll
    for (int fi = 0; fi < 4; ++fi)
#pragma unroll
      for (int fj = 0; fj < 2; ++fj)
        acc[fi][fj] = __builtin_amdgcn_mfma_f32_16x16x32_bf16(
            af[fi], use[fj], acc[fi][fj], 0, 0, 0);
  };

  for (int ct = 0; ct < 3; ++ct) {
#pragma unroll
    for (int i = 0; i < 4; ++i)
#pragma unroll
      for (int j = 0; j < 2; ++j) acc[i][j] = (f32x4){0.f, 0.f, 0.f, 0.f};

    for (int j2 = 0; j2 < 12; ++j2) {  // static ping/pong (rule #20)
      step(ct * 24 + j2 * 2, bA, bB);
      step(ct * 24 + j2 * 2 + 1, bB, bA);
    }
    // epilogue: ct selects q/k/v exactly. C/D col = lane&15, row=(l>>4)*4+reg
    float* dst = (ct == 0) ? q : (ct == 1) ? kk : v;
#pragma unroll
    for (int fj = 0; fj < 2; ++fj) {
      const int col = wc + fj * 16 + l15;  // 0..255 within this tensor
      const int hh = col >> 5, cc = col & 31;
      const float bv = bias[ct * 256 + col];
#pragma unroll
      for (int fi = 0; fi < 4; ++fi) {
#pragma unroll
        for (int jj = 0; jj < 4; ++jj) {
          const int rr = row0 + fi * 16 + l4 * 4 + jj;
          const int bb = rr >> 12, n = rr & 4095;
          dst[((size_t)(bb * 8 + hh) * 4096 + n) * 32 + cc] =
              acc[fi][fj][jj] + bv;
        }
      }
    }
  }
}

// ---- ktv partials (no max-subtract: |k| <~ 2, exp() is safe in fp32) ------
__global__ __launch_bounds__(256) void ktv_partial_kernel(
    const float* __restrict__ k, const float* __restrict__ v,
    float* __restrict__ pev, float* __restrict__ pe) {
  const int bh = blockIdx.x;     // 0..63
  const int chunk = blockIdx.y;  // 0..15 (256 rows each)
  const float* kb = k + (size_t)bh * 131072 + (size_t)chunk * 256 * 32;
  const float* vb = v + (size_t)bh * 131072 + (size_t)chunk * 256 * 32;
  __shared__ __align__(16) float ks[32][32];
  __shared__ __align__(16) float vs[32][32];
  const int t = threadIdx.x;
  const int kc = t >> 3;       // 0..31
  const int vg = (t & 7) * 4;  // 0,4,...,28
  const int sr = t >> 3, sc = (t & 7) * 4;  // staging coords (float4)
  float a0 = 0.f, a1 = 0.f, a2 = 0.f, a3 = 0.f, se = 0.f;
  for (int n0 = 0; n0 < 256; n0 += 32) {
    __syncthreads();
    const float4 k4 =
        *reinterpret_cast<const float4*>(&kb[(size_t)(n0 + sr) * 32 + sc]);
    const float4 v4 =
        *reinterpret_cast<const float4*>(&vb[(size_t)(n0 + sr) * 32 + sc]);
    *reinterpret_cast<float4*>(&ks[sr][sc]) = k4;
    *reinterpret_cast<float4*>(&vs[sr][sc]) = v4;
    __syncthreads();
#pragma unroll
    for (int r = 0; r < 32; ++r) {
      const float e = __expf(ks[r][kc]);
      se += e;  // 8 threads sharing kc accumulate identical sums
      const float4 vv = *reinterpret_cast<const float4*>(&vs[r][vg]);
      a0 = fmaf(e, vv.x, a0); a1 = fmaf(e, vv.y, a1);
      a2 = fmaf(e, vv.z, a2); a3 = fmaf(e, vv.w, a3);
    }
  }
  float* o = pev + ((size_t)(bh * 16 + chunk)) * 1024 + kc * 32 + vg;
  o[0] = a0; o[1] = a1; o[2] = a2; o[3] = a3;
  if ((t & 7) == 0) pe[(bh * 16 + chunk) * 32 + kc] = se;
}

// ---- ktv reduce: ktv[bh,kc,vc] = sum_ch pev / sum_ch pe -------------------
__global__ __launch_bounds__(256) void ktv_reduce_kernel(
    const float* __restrict__ pev, const float* __restrict__ pe,
    float* __restrict__ ktv) {
  const int bh = blockIdx.x;
  const int t = threadIdx.x;
  const int kc = t >> 3, vg = (t & 7) * 4;
  float a0 = 0.f, a1 = 0.f, a2 = 0.f, a3 = 0.f, se = 0.f;
  for (int ch = 0; ch < 16; ++ch) {
    const float4 p4 = *reinterpret_cast<const float4*>(
        &pev[((size_t)(bh * 16 + ch)) * 1024 + kc * 32 + vg]);
    a0 += p4.x; a1 += p4.y; a2 += p4.z; a3 += p4.w;
    se += pe[(bh * 16 + ch) * 32 + kc];
  }
  const float inv = 1.0f / se;
  float* o = ktv + (size_t)bh * 1024 + kc * 32 + vg;
  o[0] = a0 * inv; o[1] = a1 * inv; o[2] = a2 * inv; o[3] = a3 * inv;
}

// ------------------- CRPE depthwise conv (3/5/7 by head group) -------------
template <int K>
__device__ __forceinline__ void crpe_tile(const float (*lds)[64][32],
                                          const float* __restrict__ wch,
                                          float bias, int c, int x0,
                                          float* __restrict__ outbase) {
  constexpr int P = K / 2;
  constexpr int W = 8 + K - 1;
  float wreg[K * K];
#pragma unroll
  for (int i = 0; i < K * K; ++i) wreg[i] = wch[i];
#pragma unroll
  for (int yy = 0; yy < 4; ++yy) {
    float acc[8];
#pragma unroll
    for (int i = 0; i < 8; ++i) acc[i] = bias;
#pragma unroll
    for (int ky = 0; ky < K; ++ky) {
      const int lrow = yy + ky + (3 - P);
      float win[W];
#pragma unroll
      for (int j = 0; j < W; ++j) {
        const int xx = x0 + j - P;
        const int xc = min(max(xx, 0), 63);
        const float val = lds[lrow][xc][c];
        win[j] = (xx == xc) ? val : 0.f;
      }
#pragma unroll
      for (int kx = 0; kx < K; ++kx) {
        const float wgt = wreg[ky * K + kx];
#pragma unroll
        for (int i = 0; i < 8; ++i) acc[i] = fmaf(win[i + kx], wgt, acc[i]);
      }
    }
#pragma unroll
    for (int i = 0; i < 8; ++i)
      outbase[(size_t)(yy * 64 + x0 + i) * 32 + c] = acc[i];
  }
}

__global__ __launch_bounds__(256) void crpe_conv_kernel(
    const float* __restrict__ v, const float* __restrict__ w3,
    const float* __restrict__ b3, const float* __restrict__ w5,
    const float* __restrict__ b5, const float* __restrict__ w7,
    const float* __restrict__ b7, float* __restrict__ convv) {
  __shared__ __align__(16) float lds[10][64][32];  // 80 KB
  const int t = threadIdx.x;
  const int y0 = blockIdx.x * 4;
  const int h = blockIdx.y, b = blockIdx.z;
  const float* vb = v + (size_t)(b * 8 + h) * 131072;
  const int ytop = y0 - 3;
  float4* lds4 = reinterpret_cast<float4*>(&lds[0][0][0]);
#pragma unroll
  for (int i = 0; i < 20; ++i) {
    const int idx = t + i * 256;  // float4 index, 512 per row
    const int row = idx >> 9;
    const int y = ytop + row;
    float4 val = {0.f, 0.f, 0.f, 0.f};
    if (y >= 0 && y < 64)
      val = *reinterpret_cast<const float4*>(
          &vb[(size_t)y * 2048 + (size_t)(idx & 511) * 4]);
    lds4[idx] = val;
  }
  __syncthreads();
  const int c = t & 31;
  const int x0 = (t >> 5) * 8;
  const int ch = h * 32 + c;
  float* outbase = convv + ((size_t)(b * 8 + h) * 4096 + y0 * 64) * 32;
  if (h < 2)
    crpe_tile<3>(lds, w3 + ch * 9, b3[ch], c, x0, outbase);
  else if (h < 5)
    crpe_tile<5>(lds, w5 + (ch - 64) * 25, b5[ch - 64], c, x0, outbase);
  else
    crpe_tile<7>(lds, w7 + (ch - 160) * 49, b7[ch - 160], c, x0, outbase);
}

// ------ fa = SCALE*q@ktv + q*conv_v ; write fa + per-block pooled partial --
__global__ __launch_bounds__(256) void factor_att_kernel(
    const float* __restrict__ q, const float* __restrict__ convv,
    const float* __restrict__ ktv, float* __restrict__ fa,
    float* __restrict__ partial) {
  const int b = blockIdx.z, h = blockIdx.y;
  const int n0 = blockIdx.x * 64;
  __shared__ __align__(16) float kt[32][32];
  __shared__ float qs[8][32];
  __shared__ float ps[8][32];
  const int t = threadIdx.x;
#pragma unroll
  for (int i = 0; i < 4; ++i) {
    const int idx = t + i * 256;
    kt[idx >> 5][idx & 31] = ktv[(size_t)(b * 8 + h) * 1024 + idx];
  }
  const size_t off = ((size_t)(b * 8 + h) * 4096 + n0) * 32;
  const float* qb = q + off;
  const float* cb = convv + off;
  float* fb = fa + off;
  const int c = t & 31, rs = t >> 5;
  float pool = 0.f;
  for (int i = 0; i < 8; ++i) {
    __syncthreads();
    qs[rs][c] = qb[i * 256 + t];
    __syncthreads();
    float s = 0.f;
#pragma unroll
    for (int kc = 0; kc < 32; ++kc) s = fmaf(qs[rs][kc], kt[kc][c], s);
    const float val = kScale * s + qs[rs][c] * cb[i * 256 + t];
    fb[i * 256 + t] = val;
    pool += val;
  }
  __syncthreads();
  ps[rs][c] = pool;
  __syncthreads();
  if (t < 32) {
    float s = 0.f;
#pragma unroll
    for (int r = 0; r < 8; ++r) s += ps[r][t];
    partial[((size_t)(b * 8 + h) * 64 + blockIdx.x) * 32 + t] = s;
  }
}

// ------------------ SE MLP -> gfac[b][h] = 1 + sigmoid(...) ----------------
__global__ __launch_bounds__(256) void se_kernel(
    const float* __restrict__ partial, const float* __restrict__ w1,
    const float* __restrict__ w2, float* __restrict__ gfac) {
  const int b = blockIdx.x, t = threadIdx.x;
  __shared__ float pm[256];
  __shared__ float hid[128];
  {
    const int h = t >> 5, c = t & 31;
    const float* p = partial + ((size_t)(b * 8 + h) * 64) * 32 + c;
    float s = 0.f;
#pragma unroll 8
    for (int nc = 0; nc < 64; ++nc) s += p[nc * 32];
    pm[t] = s * (1.0f / 4096.0f);
  }
  __syncthreads();
  if (t < 128) {
    float s = 0.f;
    for (int ch = 0; ch < 256; ++ch) s = fmaf(pm[ch], w1[t * 256 + ch], s);
    hid[t] = fmaxf(s, 0.f);
  }
  __syncthreads();
  if (t < 8) {
    float g = 0.f;
    for (int j = 0; j < 128; ++j) g = fmaf(hid[j], w2[t * 128 + j], g);
    gfac[b * 8 + t] = 1.0f + 1.0f / (1.0f + __expf(-g));
  }
}

// ------- proj GEMM: 64-row panels, direct-B, barrier-free K-loop -----------
__global__ __launch_bounds__(512, 4) void proj_mfma_kernel(
    const float* __restrict__ fa, const float* __restrict__ gfac,
    const short* __restrict__ pwsplit, const float* __restrict__ bias,
    float* __restrict__ out) {
  __shared__ short As[64][520];  // [row][hi(256) | lo(256)] -> 66.6 KB
  const int tid = threadIdx.x;
  const int row0 = blockIdx.x * 64;
  const int wave = tid >> 6, lane = tid & 63;
  const int wc = wave * 32;
  const int l15 = lane & 15, l4 = lane >> 4;
  const int b = row0 >> 12;  // 64 | 4096: panel never straddles batches

  const short* bbase = pwsplit + (size_t)(wc + l15) * 32 + l4 * 8;
  bf16x8 bA[2], bB[2];
  auto bload = [&](int nc, bf16x8 (&bb)[2]) {
#pragma unroll
    for (int f = 0; f < 2; ++f)
      bb[f] = *reinterpret_cast<const bf16x8*>(bbase + (size_t)nc * 8192 +
                                               f * 512);
  };
  bload(0, bA);

  // stage A panel: fa[b, c/32, n, c%32] * gfac, split hi/lo
#pragma unroll 4
  for (int i = 0; i < 8; ++i) {
    const int f = tid + i * 512;             // float4 index
    const int r = f >> 6, c = (f & 63) * 4;  // row, flat col (0..252, 4-align)
    const int hh = c >> 5, cc = c & 31;      // 4 cols stay in one head
    const int n = (row0 & 4095) + r;
    const float g = gfac[b * 8 + hh];
    float4 a4 = *reinterpret_cast<const float4*>(
        &fa[((size_t)(b * 8 + hh) * 4096 + n) * 32 + cc]);
    a4.x *= g; a4.y *= g; a4.z *= g; a4.w *= g;
    bf16x4 h, l;
    h[0] = bf_hi(a4.x); h[1] = bf_hi(a4.y); h[2] = bf_hi(a4.z);
    h[3] = bf_hi(a4.w);
    l[0] = bf_lo(a4.x); l[1] = bf_lo(a4.y); l[2] = bf_lo(a4.z);
    l[3] = bf_lo(a4.w);
    *reinterpret_cast<bf16x4*>(&As[r][c]) = h;
    *reinterpret_cast<bf16x4*>(&As[r][256 + c]) = l;
  }
  __syncthreads();  // only barrier

  f32x4 acc[4][2];
#pragma unroll
  for (int i = 0; i < 4; ++i)
#pragma unroll
    for (int j = 0; j < 2; ++j) acc[i][j] = (f32x4){0.f, 0.f, 0.f, 0.f};

  auto step = [&](int nc, bf16x8 (&use)[2], bf16x8 (&pf)[2]) {
    if (nc + 1 < 24) bload(nc + 1, pf);
    const int r = nc >> 3, kc = nc & 7;
    const int aoff = (r == 2 ? 256 : 0) + kc * 32;
    bf16x8 af[4];
#pragma unroll
    for (int f = 0; f < 4; ++f)
      af[f] = *reinterpret_cast<const bf16x8*>(
          &As[f * 16 + l15][aoff + l4 * 8]);
#pragma unroll
    for (int fi = 0; fi < 4; ++fi)
#pragma unroll
      for (int fj = 0; fj < 2; ++fj)
        acc[fi][fj] = __builtin_amdgcn_mfma_f32_16x16x32_bf16(
            af[fi], use[fj], acc[fi][fj], 0, 0, 0);
  };

  for (int j2 = 0; j2 < 12; ++j2) {  // static ping/pong (rule #20)
    step(j2 * 2, bA, bB);
    step(j2 * 2 + 1, bB, bA);
  }
  // epilogue: out row-major, coalesced. C/D col = lane&15, row=(l>>4)*4+reg
#pragma unroll
  for (int fj = 0; fj < 2; ++fj) {
    const int col = wc + fj * 16 + l15;
    const float bv = bias[col];
#pragma unroll
    for (int fi = 0; fi < 4; ++fi) {
#pragma unroll
      for (int jj = 0; jj < 4; ++jj) {
        const int rr = row0 + fi * 16 + l4 * 4 + jj;
        out[(size_t)rr * 256 + col] = acc[fi][fj][jj] + bv;
      }
    }
  }
}

}  // namespace

extern "C" void kernel_launch(void* const* d_in, const int* in_sizes, int n_in,
                              void* d_out, int out_size, void* d_ws,
                              size_t ws_size, hipStream_t stream) {
  const float* x      = (const float*)d_in[0];
  const float* qkv_w  = (const float*)d_in[1];
  const float* qkv_b  = (const float*)d_in[2];
  const float* proj_w = (const float*)d_in[3];
  const float* proj_b = (const float*)d_in[4];
  const float* se_w1  = (const float*)d_in[5];
  const float* se_w2  = (const float*)d_in[6];
  const float* w3 = (const float*)d_in[7];
  const float* b3 = (const float*)d_in[8];
  const float* w5 = (const float*)d_in[9];
  const float* b5 = (const float*)d_in[10];
  const float* w7 = (const float*)d_in[11];
  const float* b7 = (const float*)d_in[12];
  float* out = (float*)d_out;
  float* ws = (float*)d_ws;

  const size_t SZ = (size_t)8 * 8 * 4096 * 32;  // 8388608 floats per tensor
  float* q       = ws;                //  q [B,h,N,Ch]; dead after factor_att
  float* kbuf    = ws + SZ;           //  k  -> conv_v after ktv
  float* vbuf    = ws + 2 * SZ;       //  v  -> fa after conv
  float* ktv     = ws + 3 * SZ;       //  64*1024
  float* kmaxp   = ktv + 65536;       //  (unused now)
  float* partial = kmaxp + 16384;     //  4096*32
  float* gfac    = partial + 131072;  //  64
  // d_out scratch: pev/pe for ktv, wsplit2 for qkv — consumed before proj.
  // pwsplit lives in the q buffer (dead after factor_att), since proj
  // overwrites all of d_out while reading pwsplit.
  float* pev = out;                        //  64*16*1024 = 1,048,576 floats
  float* pe  = out + 64 * 16 * 1024;       //  64*16*32   =    32,768 floats
  short* wsplit2 = (short*)(out + 2 * 1024 * 1024);  // 72*8192 shorts, 1.15MB
  short* pwsplit = (short*)q;                        // 24*8192 shorts, 384KB
  (void)ws_size; (void)in_sizes; (void)n_in; (void)out_size;

  wsplit2_kernel<<<72, 1024, 0, stream>>>(qkv_w, wsplit2);
  qkv_mfma_kernel<<<512, 512, 0, stream>>>(x, wsplit2, qkv_b, q, kbuf, vbuf);
  ktv_partial_kernel<<<dim3(64, 16), 256, 0, stream>>>(kbuf, vbuf, pev, pe);
  ktv_reduce_kernel<<<64, 256, 0, stream>>>(pev, pe, ktv);
  crpe_conv_kernel<<<dim3(16, 8, 8), 256, 0, stream>>>(vbuf, w3, b3, w5, b5,
                                                       w7, b7, kbuf);
  factor_att_kernel<<<dim3(64, 8, 8), 256, 0, stream>>>(q, kbuf, ktv, vbuf,
                                                        partial);
  se_kernel<<<8, 256, 0, stream>>>(partial, se_w1, se_w2, gfac);
  pwsplit_kernel<<<24, 1024, 0, stream>>>(proj_w, pwsplit);
  proj_mfma_kernel<<<512, 512, 0, stream>>>(vbuf, gfac, pwsplit, proj_b, out);
}

// Round 14
// 178.021 us; speedup vs baseline: 1.3298x; 1.3298x over previous
//
#include <hip/hip_runtime.h>

namespace {

constexpr float kScale = 0.17677669529663687f;  // 32^-0.5

typedef __attribute__((ext_vector_type(8))) short bf16x8;
typedef __attribute__((ext_vector_type(4))) short bf16x4;
typedef __attribute__((ext_vector_type(4))) float f32x4;

// RNE fp32 -> bf16 (bit pattern in short)
__device__ __forceinline__ short bf_hi(float x) {
  unsigned u = __float_as_uint(x);
  return (short)((u + 0x7FFFu + ((u >> 16) & 1u)) >> 16);
}
// residual term: bf16(x - float(bf16(x)))
__device__ __forceinline__ short bf_lo(float x) {
  unsigned u = __float_as_uint(x);
  unsigned hi = (u + 0x7FFFu + ((u >> 16) & 1u)) & 0xFFFF0000u;
  float r = x - __uint_as_float(hi);
  unsigned u2 = __float_as_uint(r);
  return (short)((u2 + 0x7FFFu + ((u2 >> 16) & 1u)) >> 16);
}

__device__ __forceinline__ bf16x8 cvt8v(const float4 f0, const float4 f1,
                                        bool lo) {
  bf16x8 v;
  if (lo) {
    v[0] = bf_lo(f0.x); v[1] = bf_lo(f0.y); v[2] = bf_lo(f0.z);
    v[3] = bf_lo(f0.w); v[4] = bf_lo(f1.x); v[5] = bf_lo(f1.y);
    v[6] = bf_lo(f1.z); v[7] = bf_lo(f1.w);
  } else {
    v[0] = bf_hi(f0.x); v[1] = bf_hi(f0.y); v[2] = bf_hi(f0.z);
    v[3] = bf_hi(f0.w); v[4] = bf_hi(f1.x); v[5] = bf_hi(f1.y);
    v[6] = bf_hi(f1.z); v[7] = bf_hi(f1.w);
  }
  return v;
}

// ---- wsplit2: emit qkv B operand in per-chunk layout [72][256 col][32 k] --
__global__ __launch_bounds__(1024) void wsplit2_kernel(
    const float* __restrict__ w, short* __restrict__ wsplit2) {
  const int nc = blockIdx.x;  // 0..71
  const int ct = nc / 24, j = nc % 24;
  const int r = j >> 3, kc = j & 7;
  const bool lo = (r == 1);
  const int u = threadIdx.x;           // 0..1023
  const int col = u >> 2, kq = u & 3;  // 8 shorts per thread
  const float* src = &w[(size_t)(ct * 256 + col) * 256 + kc * 32 + kq * 8];
  const float4 f0 = *reinterpret_cast<const float4*>(src);
  const float4 f1 = *reinterpret_cast<const float4*>(src + 4);
  *reinterpret_cast<bf16x8*>(&wsplit2[(size_t)nc * 8192 + u * 8]) =
      cvt8v(f0, f1, lo);
}

// ---- pwsplit: same layout for proj_w: [24][256 col][32 k] -----------------
__global__ __launch_bounds__(1024) void pwsplit_kernel(
    const float* __restrict__ w, short* __restrict__ pw) {
  const int nc = blockIdx.x;  // 0..23
  const int r = nc >> 3, kc = nc & 7;
  const bool lo = (r == 1);
  const int u = threadIdx.x;
  const int col = u >> 2, kq = u & 3;
  const float* src = &w[(size_t)col * 256 + kc * 32 + kq * 8];
  const float4 f0 = *reinterpret_cast<const float4*>(src);
  const float4 f1 = *reinterpret_cast<const float4*>(src + 4);
  *reinterpret_cast<bf16x8*>(&pw[(size_t)nc * 8192 + u * 8]) =
      cvt8v(f0, f1, lo);
}

// ---------------- qkv GEMM via split-bf16 MFMA, 64-row panels --------------
// One block (512 thr = 8 waves) per 64-row panel; 66.6 KB LDS -> 2 blocks/CU
// = 4 waves/SIMD. launch_bounds(512, 2): 2nd arg is min BLOCKS/CU (observed
// R13: (512,4) forced VGPR=64 -> spills -> 460 MB HBM amplification). Cap 2
// blocks -> 128 VGPR, kernel needs ~90 -> no spills.
__global__ __launch_bounds__(512, 2) void qkv_mfma_kernel(
    const float* __restrict__ x, const short* __restrict__ wsplit2,
    const float* __restrict__ bias, float* __restrict__ q,
    float* __restrict__ kk, float* __restrict__ v) {
  __shared__ short As[64][520];  // [row][xh(256) | xl(256)] -> 66.6 KB
  const int tid = threadIdx.x;
  const int row0 = blockIdx.x * 64;
  const int wave = tid >> 6, lane = tid & 63;
  const int wc = wave * 32;  // 8 waves x 32 cols = 256 cols per pass
  const int l15 = lane & 15, l4 = lane >> 4;

  // per-lane B fragment base: row (wc + f*16 + l15), k-slice l4*8
  const short* bbase = wsplit2 + (size_t)(wc + l15) * 32 + l4 * 8;
  bf16x8 bA[2], bB[2];
  auto bload = [&](int nc, bf16x8 (&b)[2]) {
#pragma unroll
    for (int f = 0; f < 2; ++f)
      b[f] = *reinterpret_cast<const bf16x8*>(bbase + (size_t)nc * 8192 +
                                              f * 512);
  };
  bload(0, bA);

  // stage A panel: 64 rows x 64 float4 = 4096 float4s, split to hi/lo
#pragma unroll 4
  for (int i = 0; i < 8; ++i) {
    const int f = tid + i * 512;             // float4 index
    const int r = f >> 6, c = (f & 63) * 4;  // row, col(0..252)
    const float4 a4 = *reinterpret_cast<const float4*>(
        &x[(size_t)(row0 + r) * 256 + c]);
    bf16x4 h, l;
    h[0] = bf_hi(a4.x); h[1] = bf_hi(a4.y); h[2] = bf_hi(a4.z);
    h[3] = bf_hi(a4.w);
    l[0] = bf_lo(a4.x); l[1] = bf_lo(a4.y); l[2] = bf_lo(a4.z);
    l[3] = bf_lo(a4.w);
    *reinterpret_cast<bf16x4*>(&As[r][c]) = h;
    *reinterpret_cast<bf16x4*>(&As[r][256 + c]) = l;
  }
  __syncthreads();  // the only barrier: As is read-only from here on

  f32x4 acc[4][2];
  // one chunk: prefetch nc+1 into pf, consume use
  auto step = [&](int nc, bf16x8 (&use)[2], bf16x8 (&pf)[2]) {
    if (nc + 1 < 72) bload(nc + 1, pf);
    const int j = nc % 24;
    const int r = j >> 3, kc = j & 7;
    const int aoff = (r == 2 ? 256 : 0) + kc * 32;
    bf16x8 af[4];
#pragma unroll
    for (int f = 0; f < 4; ++f)
      af[f] = *reinterpret_cast<const bf16x8*>(
          &As[f * 16 + l15][aoff + l4 * 8]);
#pragma unroll
    for (int fi = 0; fi < 4; ++fi)
#pragma unroll
      for (int fj = 0; fj < 2; ++fj)
        acc[fi][fj] = __builtin_amdgcn_mfma_f32_16x16x32_bf16(
            af[fi], use[fj], acc[fi][fj], 0, 0, 0);
  };

  for (int ct = 0; ct < 3; ++ct) {
#pragma unroll
    for (int i = 0; i < 4; ++i)
#pragma unroll
      for (int j = 0; j < 2; ++j) acc[i][j] = (f32x4){0.f, 0.f, 0.f, 0.f};

    for (int j2 = 0; j2 < 12; ++j2) {  // static ping/pong (rule #20)
      step(ct * 24 + j2 * 2, bA, bB);
      step(ct * 24 + j2 * 2 + 1, bB, bA);
    }
    // epilogue: ct selects q/k/v exactly. C/D col = lane&15, row=(l>>4)*4+reg
    float* dst = (ct == 0) ? q : (ct == 1) ? kk : v;
#pragma unroll
    for (int fj = 0; fj < 2; ++fj) {
      const int col = wc + fj * 16 + l15;  // 0..255 within this tensor
      const int hh = col >> 5, cc = col & 31;
      const float bv = bias[ct * 256 + col];
#pragma unroll
      for (int fi = 0; fi < 4; ++fi) {
#pragma unroll
        for (int jj = 0; jj < 4; ++jj) {
          const int rr = row0 + fi * 16 + l4 * 4 + jj;
          const int bb = rr >> 12, n = rr & 4095;
          dst[((size_t)(bb * 8 + hh) * 4096 + n) * 32 + cc] =
              acc[fi][fj][jj] + bv;
        }
      }
    }
  }
}

// ---- ktv partials (no max-subtract: |k| <~ 2, exp() is safe in fp32) ------
__global__ __launch_bounds__(256) void ktv_partial_kernel(
    const float* __restrict__ k, const float* __restrict__ v,
    float* __restrict__ pev, float* __restrict__ pe) {
  const int bh = blockIdx.x;     // 0..63
  const int chunk = blockIdx.y;  // 0..15 (256 rows each)
  const float* kb = k + (size_t)bh * 131072 + (size_t)chunk * 256 * 32;
  const float* vb = v + (size_t)bh * 131072 + (size_t)chunk * 256 * 32;
  __shared__ __align__(16) float ks[32][32];
  __shared__ __align__(16) float vs[32][32];
  const int t = threadIdx.x;
  const int kc = t >> 3;       // 0..31
  const int vg = (t & 7) * 4;  // 0,4,...,28
  const int sr = t >> 3, sc = (t & 7) * 4;  // staging coords (float4)
  float a0 = 0.f, a1 = 0.f, a2 = 0.f, a3 = 0.f, se = 0.f;
  for (int n0 = 0; n0 < 256; n0 += 32) {
    __syncthreads();
    const float4 k4 =
        *reinterpret_cast<const float4*>(&kb[(size_t)(n0 + sr) * 32 + sc]);
    const float4 v4 =
        *reinterpret_cast<const float4*>(&vb[(size_t)(n0 + sr) * 32 + sc]);
    *reinterpret_cast<float4*>(&ks[sr][sc]) = k4;
    *reinterpret_cast<float4*>(&vs[sr][sc]) = v4;
    __syncthreads();
#pragma unroll
    for (int r = 0; r < 32; ++r) {
      const float e = __expf(ks[r][kc]);
      se += e;  // 8 threads sharing kc accumulate identical sums
      const float4 vv = *reinterpret_cast<const float4*>(&vs[r][vg]);
      a0 = fmaf(e, vv.x, a0); a1 = fmaf(e, vv.y, a1);
      a2 = fmaf(e, vv.z, a2); a3 = fmaf(e, vv.w, a3);
    }
  }
  float* o = pev + ((size_t)(bh * 16 + chunk)) * 1024 + kc * 32 + vg;
  o[0] = a0; o[1] = a1; o[2] = a2; o[3] = a3;
  if ((t & 7) == 0) pe[(bh * 16 + chunk) * 32 + kc] = se;
}

// ---- ktv reduce: ktv[bh,kc,vc] = sum_ch pev / sum_ch pe -------------------
__global__ __launch_bounds__(256) void ktv_reduce_kernel(
    const float* __restrict__ pev, const float* __restrict__ pe,
    float* __restrict__ ktv) {
  const int bh = blockIdx.x;
  const int t = threadIdx.x;
  const int kc = t >> 3, vg = (t & 7) * 4;
  float a0 = 0.f, a1 = 0.f, a2 = 0.f, a3 = 0.f, se = 0.f;
  for (int ch = 0; ch < 16; ++ch) {
    const float4 p4 = *reinterpret_cast<const float4*>(
        &pev[((size_t)(bh * 16 + ch)) * 1024 + kc * 32 + vg]);
    a0 += p4.x; a1 += p4.y; a2 += p4.z; a3 += p4.w;
    se += pe[(bh * 16 + ch) * 32 + kc];
  }
  const float inv = 1.0f / se;
  float* o = ktv + (size_t)bh * 1024 + kc * 32 + vg;
  o[0] = a0 * inv; o[1] = a1 * inv; o[2] = a2 * inv; o[3] = a3 * inv;
}

// ------------------- CRPE depthwise conv (3/5/7 by head group) -------------
template <int K>
__device__ __forceinline__ void crpe_tile(const float (*lds)[64][32],
                                          const float* __restrict__ wch,
                                          float bias, int c, int x0,
                                          float* __restrict__ outbase) {
  constexpr int P = K / 2;
  constexpr int W = 8 + K - 1;
  float wreg[K * K];
#pragma unroll
  for (int i = 0; i < K * K; ++i) wreg[i] = wch[i];
#pragma unroll
  for (int yy = 0; yy < 4; ++yy) {
    float acc[8];
#pragma unroll
    for (int i = 0; i < 8; ++i) acc[i] = bias;
#pragma unroll
    for (int ky = 0; ky < K; ++ky) {
      const int lrow = yy + ky + (3 - P);
      float win[W];
#pragma unroll
      for (int j = 0; j < W; ++j) {
        const int xx = x0 + j - P;
        const int xc = min(max(xx, 0), 63);
        const float val = lds[lrow][xc][c];
        win[j] = (xx == xc) ? val : 0.f;
      }
#pragma unroll
      for (int kx = 0; kx < K; ++kx) {
        const float wgt = wreg[ky * K + kx];
#pragma unroll
        for (int i = 0; i < 8; ++i) acc[i] = fmaf(win[i + kx], wgt, acc[i]);
      }
    }
#pragma unroll
    for (int i = 0; i < 8; ++i)
      outbase[(size_t)(yy * 64 + x0 + i) * 32 + c] = acc[i];
  }
}

__global__ __launch_bounds__(256) void crpe_conv_kernel(
    const float* __restrict__ v, const float* __restrict__ w3,
    const float* __restrict__ b3, const float* __restrict__ w5,
    const float* __restrict__ b5, const float* __restrict__ w7,
    const float* __restrict__ b7, float* __restrict__ convv) {
  __shared__ __align__(16) float lds[10][64][32];  // 80 KB
  const int t = threadIdx.x;
  const int y0 = blockIdx.x * 4;
  const int h = blockIdx.y, b = blockIdx.z;
  const float* vb = v + (size_t)(b * 8 + h) * 131072;
  const int ytop = y0 - 3;
  float4* lds4 = reinterpret_cast<float4*>(&lds[0][0][0]);
#pragma unroll
  for (int i = 0; i < 20; ++i) {
    const int idx = t + i * 256;  // float4 index, 512 per row
    const int row = idx >> 9;
    const int y = ytop + row;
    float4 val = {0.f, 0.f, 0.f, 0.f};
    if (y >= 0 && y < 64)
      val = *reinterpret_cast<const float4*>(
          &vb[(size_t)y * 2048 + (size_t)(idx & 511) * 4]);
    lds4[idx] = val;
  }
  __syncthreads();
  const int c = t & 31;
  const int x0 = (t >> 5) * 8;
  const int ch = h * 32 + c;
  float* outbase = convv + ((size_t)(b * 8 + h) * 4096 + y0 * 64) * 32;
  if (h < 2)
    crpe_tile<3>(lds, w3 + ch * 9, b3[ch], c, x0, outbase);
  else if (h < 5)
    crpe_tile<5>(lds, w5 + (ch - 64) * 25, b5[ch - 64], c, x0, outbase);
  else
    crpe_tile<7>(lds, w7 + (ch - 160) * 49, b7[ch - 160], c, x0, outbase);
}

// ------ fa = SCALE*q@ktv + q*conv_v ; write fa + per-block pooled partial --
__global__ __launch_bounds__(256) void factor_att_kernel(
    const float* __restrict__ q, const float* __restrict__ convv,
    const float* __restrict__ ktv, float* __restrict__ fa,
    float* __restrict__ partial) {
  const int b = blockIdx.z, h = blockIdx.y;
  const int n0 = blockIdx.x * 64;
  __shared__ __align__(16) float kt[32][32];
  __shared__ float qs[8][32];
  __shared__ float ps[8][32];
  const int t = threadIdx.x;
#pragma unroll
  for (int i = 0; i < 4; ++i) {
    const int idx = t + i * 256;
    kt[idx >> 5][idx & 31] = ktv[(size_t)(b * 8 + h) * 1024 + idx];
  }
  const size_t off = ((size_t)(b * 8 + h) * 4096 + n0) * 32;
  const float* qb = q + off;
  const float* cb = convv + off;
  float* fb = fa + off;
  const int c = t & 31, rs = t >> 5;
  float pool = 0.f;
  for (int i = 0; i < 8; ++i) {
    __syncthreads();
    qs[rs][c] = qb[i * 256 + t];
    __syncthreads();
    float s = 0.f;
#pragma unroll
    for (int kc = 0; kc < 32; ++kc) s = fmaf(qs[rs][kc], kt[kc][c], s);
    const float val = kScale * s + qs[rs][c] * cb[i * 256 + t];
    fb[i * 256 + t] = val;
    pool += val;
  }
  __syncthreads();
  ps[rs][c] = pool;
  __syncthreads();
  if (t < 32) {
    float s = 0.f;
#pragma unroll
    for (int r = 0; r < 8; ++r) s += ps[r][t];
    partial[((size_t)(b * 8 + h) * 64 + blockIdx.x) * 32 + t] = s;
  }
}

// ------------------ SE MLP -> gfac[b][h] = 1 + sigmoid(...) ----------------
__global__ __launch_bounds__(256) void se_kernel(
    const float* __restrict__ partial, const float* __restrict__ w1,
    const float* __restrict__ w2, float* __restrict__ gfac) {
  const int b = blockIdx.x, t = threadIdx.x;
  __shared__ float pm[256];
  __shared__ float hid[128];
  {
    const int h = t >> 5, c = t & 31;
    const float* p = partial + ((size_t)(b * 8 + h) * 64) * 32 + c;
    float s = 0.f;
#pragma unroll 8
    for (int nc = 0; nc < 64; ++nc) s += p[nc * 32];
    pm[t] = s * (1.0f / 4096.0f);
  }
  __syncthreads();
  if (t < 128) {
    float s = 0.f;
    for (int ch = 0; ch < 256; ++ch) s = fmaf(pm[ch], w1[t * 256 + ch], s);
    hid[t] = fmaxf(s, 0.f);
  }
  __syncthreads();
  if (t < 8) {
    float g = 0.f;
    for (int j = 0; j < 128; ++j) g = fmaf(hid[j], w2[t * 128 + j], g);
    gfac[b * 8 + t] = 1.0f + 1.0f / (1.0f + __expf(-g));
  }
}

// ------- proj GEMM: 64-row panels, direct-B, barrier-free K-loop -----------
__global__ __launch_bounds__(512, 2) void proj_mfma_kernel(
    const float* __restrict__ fa, const float* __restrict__ gfac,
    const short* __restrict__ pwsplit, const float* __restrict__ bias,
    float* __restrict__ out) {
  __shared__ short As[64][520];  // [row][hi(256) | lo(256)] -> 66.6 KB
  const int tid = threadIdx.x;
  const int row0 = blockIdx.x * 64;
  const int wave = tid >> 6, lane = tid & 63;
  const int wc = wave * 32;
  const int l15 = lane & 15, l4 = lane >> 4;
  const int b = row0 >> 12;  // 64 | 4096: panel never straddles batches

  const short* bbase = pwsplit + (size_t)(wc + l15) * 32 + l4 * 8;
  bf16x8 bA[2], bB[2];
  auto bload = [&](int nc, bf16x8 (&bb)[2]) {
#pragma unroll
    for (int f = 0; f < 2; ++f)
      bb[f] = *reinterpret_cast<const bf16x8*>(bbase + (size_t)nc * 8192 +
                                               f * 512);
  };
  bload(0, bA);

  // stage A panel: fa[b, c/32, n, c%32] * gfac, split hi/lo
#pragma unroll 4
  for (int i = 0; i < 8; ++i) {
    const int f = tid + i * 512;             // float4 index
    const int r = f >> 6, c = (f & 63) * 4;  // row, flat col (0..252, 4-align)
    const int hh = c >> 5, cc = c & 31;      // 4 cols stay in one head
    const int n = (row0 & 4095) + r;
    const float g = gfac[b * 8 + hh];
    float4 a4 = *reinterpret_cast<const float4*>(
        &fa[((size_t)(b * 8 + hh) * 4096 + n) * 32 + cc]);
    a4.x *= g; a4.y *= g; a4.z *= g; a4.w *= g;
    bf16x4 h, l;
    h[0] = bf_hi(a4.x); h[1] = bf_hi(a4.y); h[2] = bf_hi(a4.z);
    h[3] = bf_hi(a4.w);
    l[0] = bf_lo(a4.x); l[1] = bf_lo(a4.y); l[2] = bf_lo(a4.z);
    l[3] = bf_lo(a4.w);
    *reinterpret_cast<bf16x4*>(&As[r][c]) = h;
    *reinterpret_cast<bf16x4*>(&As[r][256 + c]) = l;
  }
  __syncthreads();  // only barrier

  f32x4 acc[4][2];
#pragma unroll
  for (int i = 0; i < 4; ++i)
#pragma unroll
    for (int j = 0; j < 2; ++j) acc[i][j] = (f32x4){0.f, 0.f, 0.f, 0.f};

  auto step = [&](int nc, bf16x8 (&use)[2], bf16x8 (&pf)[2]) {
    if (nc + 1 < 24) bload(nc + 1, pf);
    const int r = nc >> 3, kc = nc & 7;
    const int aoff = (r == 2 ? 256 : 0) + kc * 32;
    bf16x8 af[4];
#pragma unroll
    for (int f = 0; f < 4; ++f)
      af[f] = *reinterpret_cast<const bf16x8*>(
          &As[f * 16 + l15][aoff + l4 * 8]);
#pragma unroll
    for (int fi = 0; fi < 4; ++fi)
#pragma unroll
      for (int fj = 0; fj < 2; ++fj)
        acc[fi][fj] = __builtin_amdgcn_mfma_f32_16x16x32_bf16(
            af[fi], use[fj], acc[fi][fj], 0, 0, 0);
  };

  for (int j2 = 0; j2 < 12; ++j2) {  // static ping/pong (rule #20)
    step(j2 * 2, bA, bB);
    step(j2 * 2 + 1, bB, bA);
  }
  // epilogue: out row-major, coalesced. C/D col = lane&15, row=(l>>4)*4+reg
#pragma unroll
  for (int fj = 0; fj < 2; ++fj) {
    const int col = wc + fj * 16 + l15;
    const float bv = bias[col];
#pragma unroll
    for (int fi = 0; fi < 4; ++fi) {
#pragma unroll
      for (int jj = 0; jj < 4; ++jj) {
        const int rr = row0 + fi * 16 + l4 * 4 + jj;
        out[(size_t)rr * 256 + col] = acc[fi][fj][jj] + bv;
      }
    }
  }
}

}  // namespace

extern "C" void kernel_launch(void* const* d_in, const int* in_sizes, int n_in,
                              void* d_out, int out_size, void* d_ws,
                              size_t ws_size, hipStream_t stream) {
  const float* x      = (const float*)d_in[0];
  const float* qkv_w  = (const float*)d_in[1];
  const float* qkv_b  = (const float*)d_in[2];
  const float* proj_w = (const float*)d_in[3];
  const float* proj_b = (const float*)d_in[4];
  const float* se_w1  = (const float*)d_in[5];
  const float* se_w2  = (const float*)d_in[6];
  const float* w3 = (const float*)d_in[7];
  const float* b3 = (const float*)d_in[8];
  const float* w5 = (const float*)d_in[9];
  const float* b5 = (const float*)d_in[10];
  const float* w7 = (const float*)d_in[11];
  const float* b7 = (const float*)d_in[12];
  float* out = (float*)d_out;
  float* ws = (float*)d_ws;

  const size_t SZ = (size_t)8 * 8 * 4096 * 32;  // 8388608 floats per tensor
  float* q       = ws;                //  q [B,h,N,Ch]; dead after factor_att
  float* kbuf    = ws + SZ;           //  k  -> conv_v after ktv
  float* vbuf    = ws + 2 * SZ;       //  v  -> fa after conv
  float* ktv     = ws + 3 * SZ;       //  64*1024
  float* kmaxp   = ktv + 65536;       //  (unused now)
  float* partial = kmaxp + 16384;     //  4096*32
  float* gfac    = partial + 131072;  //  64
  // d_out scratch: pev/pe for ktv, wsplit2 for qkv — consumed before proj.
  // pwsplit lives in the q buffer (dead after factor_att), since proj
  // overwrites all of d_out while reading pwsplit.
  float* pev = out;                        //  64*16*1024 = 1,048,576 floats
  float* pe  = out + 64 * 16 * 1024;       //  64*16*32   =    32,768 floats
  short* wsplit2 = (short*)(out + 2 * 1024 * 1024);  // 72*8192 shorts, 1.15MB
  short* pwsplit = (short*)q;                        // 24*8192 shorts, 384KB
  (void)ws_size; (void)in_sizes; (void)n_in; (void)out_size;

  wsplit2_kernel<<<72, 1024, 0, stream>>>(qkv_w, wsplit2);
  qkv_mfma_kernel<<<512, 512, 0, stream>>>(x, wsplit2, qkv_b, q, kbuf, vbuf);
  ktv_partial_kernel<<<dim3(64, 16), 256, 0, stream>>>(kbuf, vbuf, pev, pe);
  ktv_reduce_kernel<<<64, 256, 0, stream>>>(pev, pe, ktv);
  crpe_conv_kernel<<<dim3(16, 8, 8), 256, 0, stream>>>(vbuf, w3, b3, w5, b5,
                                                       w7, b7, kbuf);
  factor_att_kernel<<<dim3(64, 8, 8), 256, 0, stream>>>(q, kbuf, ktv, vbuf,
                                                        partial);
  se_kernel<<<8, 256, 0, stream>>>(partial, se_w1, se_w2, gfac);
  pwsplit_kernel<<<24, 1024, 0, stream>>>(proj_w, pwsplit);
  proj_mfma_kernel<<<512, 512, 0, stream>>>(vbuf, gfac, pwsplit, proj_b, out);
}